// Round 1
// baseline (1683.592 us; speedup 1.0000x reference)
//
#include <hip/hip_runtime.h>
#include <math.h>

#define B_ 2
#define S_ 8
#define N_ 150
#define H_ 128
#define F_ 40
#define EF_ 82

__device__ __forceinline__ float silu_f(float v) {
    return v / (1.0f + __expf(-v));
}

// ---------------- init h: one-hot embedding, broadcast over S ----------------
__global__ void init_h_kernel(const int* __restrict__ pep,
                              const int* __restrict__ labels,
                              const int* __restrict__ aapos,
                              float* __restrict__ h) {
    int idx = blockIdx.x * blockDim.x + threadIdx.x;
    if (idx >= B_ * N_ * F_) return;
    int f = idx % F_;
    int bi = idx / F_;
    int i = bi % N_;
    int b = bi / N_;
    int al = labels[b * N_ + i];
    int ap = aapos[b * N_ + i];            // 1..15
    int aa = pep[b * 15 + (ap - 1)];
    float v;
    if (f < 5)       v = (al == f) ? 1.0f : 0.0f;
    else if (f < 25) v = (aa == (f - 5)) ? 1.0f : 0.0f;
    else             v = ((ap - 1) == (f - 25)) ? 1.0f : 0.0f;
    for (int s = 0; s < S_; s++)
        h[(((b * S_) + s) * N_ + i) * F_ + f] = v;
}

// ---------------- restore absolute coords: x[b,s,i,d] = sum_j x[b,s,j,d]*R[b,i,j] ----
__global__ void restore_x_kernel(const float* __restrict__ x,
                                 const float* __restrict__ R,
                                 float* __restrict__ xa,
                                 float* __restrict__ x0) {
    int idx = blockIdx.x * blockDim.x + threadIdx.x;
    if (idx >= B_ * S_ * N_ * 3) return;
    int d = idx % 3;
    int i = (idx / 3) % N_;
    int bs = idx / (3 * N_);
    int b = bs / S_;
    const float* xrow = x + bs * N_ * 3 + d;
    const float* Rrow = R + (b * N_ + i) * N_;
    float acc = 0.0f;
    for (int j = 0; j < N_; j++) acc += xrow[j * 3] * Rrow[j];
    xa[idx] = acc;
    x0[idx] = acc;
}

// ---------------- edge kernel: one block per (b,s,i), 256 threads -----------------
// Thread t: channel c = t&127, k-split group g = t>>7.
// g==0 owns k = 0..39 (h_i, j-invariant -> hoisted) + k=80 (dist)
// g==1 owns k = 40..79 (h_j, 16B-aligned LDS row) + k=81 (bond)
// Weights held in registers (41 + 64 VGPRs); activations broadcast from LDS.
// cw reduction deferred: S_c[3] accumulated per channel, reduced once per block.
__global__ __launch_bounds__(256) void edge_kernel(
    const float* __restrict__ x_in,    // [B,S,N,3]
    const float* __restrict__ h_in,    // [B,S,N,F]
    const float* __restrict__ bond,    // [B,N,N]
    const float* __restrict__ emask,   // [B,N,N]
    const float* __restrict__ We1,     // [EF,H]
    const float* __restrict__ be1,     // [H]
    const float* __restrict__ We2,     // [H,H]
    const float* __restrict__ be2,     // [H]
    const float* __restrict__ Wc,      // [H]
    const float* __restrict__ bcp,     // [1]
    const float* __restrict__ tp,      // [B]  (null if !has_t)
    const float* __restrict__ wt,      // [H]
    const float* __restrict__ wbt,     // [H]
    int has_t,
    float* __restrict__ x_out,         // [B,S,N,3]
    float* __restrict__ agg_out)       // [B,S,N,H]
{
    int blk = blockIdx.x;              // bs*N + i
    int i  = blk % N_;
    int bs = blk / N_;
    int b  = bs / S_;
    int tid = threadIdx.x;
    int c = tid & (H_ - 1);
    int g = tid >> 7;

    __shared__ float hall[N_ * F_];    // all h rows for this (b,s): 24 KB
    __shared__ float diffA[N_ * 3];
    __shared__ float distA[N_];
    __shared__ float bondR[N_];
    __shared__ float emR[N_];
    __shared__ float m1p[2 * H_];
    __shared__ float m1s[H_];
    __shared__ float m2p[2 * H_];
    __shared__ float DL[3];

    // ---- weights into registers ----
    float W1r[41];
    if (g == 0) {
#pragma unroll
        for (int kk = 0; kk < 40; kk++) W1r[kk] = We1[kk * H_ + c];
        W1r[40] = We1[80 * H_ + c];                 // dist column
    } else {
#pragma unroll
        for (int kk = 0; kk < 40; kk++) W1r[kk] = We1[(40 + kk) * H_ + c];
        W1r[40] = We1[81 * H_ + c];                 // bond column
    }
    float W2r[64];
#pragma unroll
    for (int kk = 0; kk < 64; kk++) W2r[kk] = We2[(g * 64 + kk) * H_ + c];

    float bias1 = be1[c];
    if (has_t) bias1 += tp[b] * wt[c] + wbt[c];
    float bias2 = be2[c];

    // ---- stage per-(b,s) data into LDS ----
    const float* hbase = h_in + bs * N_ * F_;
    for (int idx = tid; idx < N_ * F_; idx += 256) hall[idx] = hbase[idx];
    const float* brow = bond  + (b * N_ + i) * N_;
    const float* erow = emask + (b * N_ + i) * N_;
    const float* xrow = x_in + bs * N_ * 3;
    float xi0 = xrow[i * 3 + 0];
    float xi1 = xrow[i * 3 + 1];
    float xi2 = xrow[i * 3 + 2];
    for (int jj = tid; jj < N_; jj += 256) {
        float d0 = xi0 - xrow[jj * 3 + 0];
        float d1 = xi1 - xrow[jj * 3 + 1];
        float d2 = xi2 - xrow[jj * 3 + 2];
        diffA[jj * 3 + 0] = d0;
        diffA[jj * 3 + 1] = d1;
        diffA[jj * 3 + 2] = d2;
        distA[jj] = sqrtf(d0 * d0 + d1 * d1 + d2 * d2 + 1e-12f);
        bondR[jj] = brow[jj];
        emR[jj]   = erow[jj];
    }
    __syncthreads();

    // j-invariant h_i part of GEMV1 (g==0 only)
    float p_hi = 0.0f;
    if (g == 0) {
#pragma unroll
        for (int kk = 0; kk < 40; kk++) p_hi += hall[i * F_ + kk] * W1r[kk];
    }

    float aggc = 0.0f, Sx = 0.0f, Sy = 0.0f, Sz = 0.0f;
    float Dx = 0.0f, Dy = 0.0f, Dz = 0.0f;

    for (int j = 0; j < N_; j++) {
        if (j == i) continue;                      // uniform branch, barrier-safe
        // GEMV1 partial
        float p;
        if (g == 0) {
            p = p_hi + distA[j] * W1r[40];
        } else {
            p = bondR[j] * W1r[40];
#pragma unroll
            for (int kk = 0; kk < 40; kk++) p += hall[j * F_ + kk] * W1r[kk];
        }
        m1p[tid] = p;
        __syncthreads();
        if (g == 0) {
            float v = m1p[c] + m1p[H_ + c] + bias1;
            m1s[c] = silu_f(v);
        }
        __syncthreads();
        // GEMV2 partial
        float q = 0.0f;
#pragma unroll
        for (int kk = 0; kk < 64; kk++) q += m1s[g * 64 + kk] * W2r[kk];
        m2p[tid] = q;
        __syncthreads();
        if (g == 0) {
            float v  = m2p[c] + m2p[H_ + c] + bias2;
            float mv = silu_f(v) * emR[j];
            aggc += mv;
            Sx += diffA[j * 3 + 0] * mv;
            Sy += diffA[j * 3 + 1] * mv;
            Sz += diffA[j * 3 + 2] * mv;
        }
        if (tid == 255) {
            Dx += diffA[j * 3 + 0];
            Dy += diffA[j * 3 + 1];
            Dz += diffA[j * 3 + 2];
        }
        // no barrier needed here: next write to m2p is after two barriers
    }

    int nbase = bs * N_ + i;
    if (g == 0) agg_out[nbase * H_ + c] = aggc;

    // deferred cw reduction: x_contrib_d = sum_c Wc_c*S_c[d] + bc*Dsum_d
    if (g == 0) {
        float wc = Wc[c];
        m1p[c]       = wc * Sx;
        m1p[H_ + c]  = wc * Sy;
        m2p[c]       = wc * Sz;
    }
    if (tid == 255) { DL[0] = Dx; DL[1] = Dy; DL[2] = Dz; }
    __syncthreads();
    if (tid < 3) {
        const float* base = (tid == 0) ? m1p : (tid == 1) ? (m1p + H_) : m2p;
        float ssum = 0.0f;
        for (int cc = 0; cc < H_; cc++) ssum += base[cc];
        float xo = (ssum + bcp[0] * DL[tid]) * (1.0f / (float)(N_ - 1));
        x_out[nbase * 3 + tid] = x_in[nbase * 3 + tid] + xo;
    }
}

// ---------------- h update: h_out = silu([h, agg] @ Wh + bh) ----------------
__global__ void hupd_kernel(const float* __restrict__ h_in,
                            const float* __restrict__ agg,
                            const float* __restrict__ Wh,   // [F+H, F]
                            const float* __restrict__ bh,   // [F]
                            float* __restrict__ h_out) {
    int nb = blockIdx.x;      // bs*N + i
    int tid = threadIdx.x;    // 64
    __shared__ float cat[F_ + H_];
    if (tid < F_) cat[tid] = h_in[nb * F_ + tid];
    cat[F_ + tid]      = agg[nb * H_ + tid];
    cat[F_ + 64 + tid] = agg[nb * H_ + 64 + tid];
    __syncthreads();
    if (tid < F_) {
        float acc = bh[tid];
#pragma unroll 8
        for (int k = 0; k < F_ + H_; k++) acc += cat[k] * Wh[k * F_ + tid];
        h_out[nb * F_ + tid] = silu_f(acc);
    }
}

// ---------------- output: (x - x0) * atom_mask ----------------
__global__ void final_kernel(const float* __restrict__ xc,
                             const float* __restrict__ x0,
                             const float* __restrict__ amask,
                             float* __restrict__ out) {
    int idx = blockIdx.x * blockDim.x + threadIdx.x;
    if (idx >= B_ * S_ * N_ * 3) return;
    int i = (idx / 3) % N_;
    int b = idx / (3 * N_ * S_);
    out[idx] = (xc[idx] - x0[idx]) * amask[b * N_ + i];
}

extern "C" void kernel_launch(void* const* d_in, const int* in_sizes, int n_in,
                              void* d_out, int out_size, void* d_ws, size_t ws_size,
                              hipStream_t stream) {
    const float* t     = (const float*)d_in[0];
    const float* x     = (const float*)d_in[1];
    const int*   pep   = (const int*)d_in[2];
    const int*   labels= (const int*)d_in[3];
    const int*   aapos = (const int*)d_in[4];
    const float* bond  = (const float*)d_in[5];
    const float* em    = (const float*)d_in[6];
    const float* amask = (const float*)d_in[7];
    const float* R     = (const float*)d_in[8];
    const float* W_e1  = (const float*)d_in[9];
    const float* b_e1  = (const float*)d_in[10];
    const float* W_e2  = (const float*)d_in[11];
    const float* b_e2  = (const float*)d_in[12];
    const float* W_c   = (const float*)d_in[13];
    const float* b_c   = (const float*)d_in[14];
    const float* W_h   = (const float*)d_in[15];
    const float* b_h   = (const float*)d_in[16];
    const float* w_t   = (const float*)d_in[17];
    const float* w_b_t = (const float*)d_in[18];
    const float* tW_e1 = (const float*)d_in[19];
    const float* tb_e1 = (const float*)d_in[20];
    const float* tW_e2 = (const float*)d_in[21];
    const float* tb_e2 = (const float*)d_in[22];
    const float* tW_c  = (const float*)d_in[23];
    const float* tb_c  = (const float*)d_in[24];
    float* out = (float*)d_out;

    float* ws  = (float*)d_ws;
    float* x0  = ws;                 // 7200
    float* xA  = x0 + 7200;          // 7200
    float* xB  = xA + 7200;          // 7200
    float* hA  = xB + 7200;          // 96000
    float* hB  = hA + 96000;         // 96000
    float* agg = hB + 96000;         // 307200   (total ~2.1 MB)

    const int XE = B_ * S_ * N_ * 3;   // 7200
    const int NB = B_ * S_ * N_;       // 2400

    init_h_kernel<<<(B_ * N_ * F_ + 255) / 256, 256, 0, stream>>>(pep, labels, aapos, hA);
    restore_x_kernel<<<(XE + 255) / 256, 256, 0, stream>>>(x, R, xA, x0);

    // layer 0 (with temb)
    edge_kernel<<<NB, 256, 0, stream>>>(xA, hA, bond, em,
        W_e1, b_e1, W_e2, b_e2, W_c, b_c, t, w_t, w_b_t, 1, xB, agg);
    hupd_kernel<<<NB, 64, 0, stream>>>(hA, agg, W_h, b_h, hB);

    // layer 1 (with temb)
    edge_kernel<<<NB, 256, 0, stream>>>(xB, hB, bond, em,
        W_e1 + EF_ * H_, b_e1 + H_, W_e2 + H_ * H_, b_e2 + H_,
        W_c + H_, b_c + 1, t, w_t + H_, w_b_t + H_, 1, xA, agg);
    hupd_kernel<<<NB, 64, 0, stream>>>(hB, agg, W_h + (F_ + H_) * F_, b_h + F_, hA);

    // t layer (no temb); h after this layer is unused -> skip h update
    edge_kernel<<<NB, 256, 0, stream>>>(xA, hA, bond, em,
        tW_e1, tb_e1, tW_e2, tb_e2, tW_c, tb_c, nullptr, nullptr, nullptr, 0, xB, agg);

    final_kernel<<<(XE + 255) / 256, 256, 0, stream>>>(xB, x0, amask, out);
}

// Round 2
// 395.707 us; speedup vs baseline: 4.2546x; 4.2546x over previous
//
#include <hip/hip_runtime.h>
#include <math.h>

#define B_ 2
#define S_ 8
#define N_ 150
#define H_ 128
#define F_ 40
#define EF_ 82
#define NP_ 160            // N padded to 10 j-tiles of 16
#define MP_ 136            // LDS row pitch in bf16 elems (128 + 8 pad -> 4-bank row shift)

typedef __attribute__((ext_vector_type(8))) short short8;
typedef __attribute__((ext_vector_type(4))) float float4v;

__device__ __forceinline__ float silu_f(float v) {
    return v * __builtin_amdgcn_rcpf(1.0f + __expf(-v));
}

// fp32 -> bf16 bits, round-to-nearest-even
__device__ __forceinline__ unsigned short f2bf(float f) {
    unsigned u = __builtin_bit_cast(unsigned, f);
    return (unsigned short)((u + 0x7fffu + ((u >> 16) & 1u)) >> 16);
}

// ---------------- init h: one-hot embedding, broadcast over S ----------------
__global__ void init_h_kernel(const int* __restrict__ pep,
                              const int* __restrict__ labels,
                              const int* __restrict__ aapos,
                              float* __restrict__ h) {
    int idx = blockIdx.x * blockDim.x + threadIdx.x;
    if (idx >= B_ * N_ * F_) return;
    int f = idx % F_;
    int bi = idx / F_;
    int i = bi % N_;
    int b = bi / N_;
    int al = labels[b * N_ + i];
    int ap = aapos[b * N_ + i];            // 1..15
    int aa = pep[b * 15 + (ap - 1)];
    float v;
    if (f < 5)       v = (al == f) ? 1.0f : 0.0f;
    else if (f < 25) v = (aa == (f - 5)) ? 1.0f : 0.0f;
    else             v = ((ap - 1) == (f - 25)) ? 1.0f : 0.0f;
    for (int s = 0; s < S_; s++)
        h[(((b * S_) + s) * N_ + i) * F_ + f] = v;
}

// ---------------- restore absolute coords ----------------
__global__ void restore_x_kernel(const float* __restrict__ x,
                                 const float* __restrict__ R,
                                 float* __restrict__ xa,
                                 float* __restrict__ x0) {
    int idx = blockIdx.x * blockDim.x + threadIdx.x;
    if (idx >= B_ * S_ * N_ * 3) return;
    int d = idx % 3;
    int i = (idx / 3) % N_;
    int bs = idx / (3 * N_);
    int b = bs / S_;
    const float* xrow = x + bs * N_ * 3 + d;
    const float* Rrow = R + (b * N_ + i) * N_;
    float acc = 0.0f;
    for (int j = 0; j < N_; j++) acc += xrow[j * 3] * Rrow[j];
    xa[idx] = acc;
    x0[idx] = acc;
}

// ---------------- per-node GEMV1 factorization ----------------
// Afeat[n,c] = h[n,:40] @ We1[0:40,c]  + be1[c] (+ t*wt[c] + wbt[c])
// Bfeat[n,c] = h[n,:40] @ We1[40:80,c]
__global__ void ab_kernel(const float* __restrict__ h,
                          const float* __restrict__ We1,
                          const float* __restrict__ be1,
                          const float* __restrict__ tp,
                          const float* __restrict__ wt,
                          const float* __restrict__ wbt,
                          int has_t,
                          float* __restrict__ Afeat,
                          float* __restrict__ Bfeat) {
    int n = blockIdx.x;                  // bs*N + node
    int b = n / (S_ * N_);
    int c = threadIdx.x;                 // 128
    __shared__ float hrow[F_];
    if (c < F_) hrow[c] = h[n * F_ + c];
    __syncthreads();
    float fa = be1[c];
    if (has_t) fa += tp[b] * wt[c] + wbt[c];
    float fb = 0.0f;
#pragma unroll 8
    for (int k = 0; k < F_; k++) {
        float hv = hrow[k];
        fa += hv * We1[k * H_ + c];
        fb += hv * We1[(F_ + k) * H_ + c];
    }
    Afeat[n * H_ + c] = fa;
    Bfeat[n * H_ + c] = fb;
}

// ---------------- edge kernel: block per (bs,i), MFMA GEMV2 ----------------
__global__ __launch_bounds__(256, 3) void edge_kernel(
    const float* __restrict__ x_in,    // [B,S,N,3]
    const float* __restrict__ Afeat,   // [BS*N,128]  (bias1+temb folded)
    const float* __restrict__ Bfeat,   // [BS*N,128]
    const float* __restrict__ We1,     // [82,128] rows 80/81 used (dist, bond)
    const float* __restrict__ We2,     // [128,128]
    const float* __restrict__ be2,     // [128]
    const float* __restrict__ Wc,      // [128]
    const float* __restrict__ bcp,     // [1]
    const float* __restrict__ bond,    // [B,N,N]
    const float* __restrict__ emask,   // [B,N,N]
    float* __restrict__ x_out,         // [B,S,N,3]
    float* __restrict__ agg_out)       // [BS*N,128]
{
    __shared__ __align__(16) short we2t[H_ * MP_];      // We2 transposed [c][k] bf16
    __shared__ __align__(16) short mbuf[2][16 * MP_];   // double-buffered m-tile [j][k]
    __shared__ float diffL[NP_ * 3];
    __shared__ float distL[NP_];
    __shared__ float bondL[NP_];
    __shared__ float emL[NP_];
    __shared__ float DsumL[3];
    __shared__ float wpart[4][3];

    int blk = blockIdx.x;
    int i  = blk % N_;
    int bs = blk / N_;
    int b  = bs / S_;
    int tid = threadIdx.x;
    int node = bs * N_ + i;

    float xi0 = x_in[node * 3 + 0];
    float xi1 = x_in[node * 3 + 1];
    float xi2 = x_in[node * 3 + 2];

    // ---- stage per-edge scalars ----
    if (tid < NP_) {
        int j = tid;
        float xj0 = xi0, xj1 = xi1, xj2 = xi2, bnd = 0.0f, emv = 0.0f;
        if (j < N_) {
            int nj = bs * N_ + j;
            xj0 = x_in[nj * 3 + 0];
            xj1 = x_in[nj * 3 + 1];
            xj2 = x_in[nj * 3 + 2];
            int eij = (b * N_ + i) * N_ + j;
            bnd = bond[eij];
            emv = (j == i) ? 0.0f : emask[eij];
        }
        float d0 = xi0 - xj0, d1 = xi1 - xj1, d2 = xi2 - xj2;
        diffL[j * 3 + 0] = d0;
        diffL[j * 3 + 1] = d1;
        diffL[j * 3 + 2] = d2;
        distL[j] = sqrtf(d0 * d0 + d1 * d1 + d2 * d2 + 1e-12f);
        bondL[j] = bnd;
        emL[j] = emv;
    }

    // ---- stage We2 transposed as bf16 ----
    for (int e = tid; e < H_ * H_; e += 256) {
        int k = e >> 7, c = e & (H_ - 1);
        we2t[c * MP_ + k] = (short)f2bf(We2[e]);
    }
    __syncthreads();

    // ---- Dsum[d] = sum_j diff (wave 0; pad rows are zero) ----
    if (tid < 64) {
        float p0 = 0, p1 = 0, p2 = 0;
        for (int j = tid; j < NP_; j += 64) {
            p0 += diffL[j * 3 + 0];
            p1 += diffL[j * 3 + 1];
            p2 += diffL[j * 3 + 2];
        }
        for (int s = 1; s < 64; s <<= 1) {
            p0 += __shfl_xor(p0, s, 64);
            p1 += __shfl_xor(p1, s, 64);
            p2 += __shfl_xor(p2, s, 64);
        }
        if (tid == 0) { DsumL[0] = p0; DsumL[1] = p1; DsumL[2] = p2; }
    }

    int lane = tid & 63, w = tid >> 6;
    int qd = lane >> 4, l15 = lane & 15;

    // m-compute mapping: thread owns c-pair c0={2*lane}, rows 4w..4w+3
    int c0 = 2 * lane;
    float af0  = Afeat[node * H_ + c0],     af1  = Afeat[node * H_ + c0 + 1];
    float w80a = We1[80 * H_ + c0],         w80b = We1[80 * H_ + c0 + 1];
    float w81a = We1[81 * H_ + c0],         w81b = We1[81 * H_ + c0 + 1];

    // epilogue mapping: wave w owns c-tiles {2w, 2w+1}; lane col = l15
    int ctb = w * 2;
    float b2r0 = be2[ctb * 16 + l15],       b2r1 = be2[(ctb + 1) * 16 + l15];
    float wc0  = Wc[ctb * 16 + l15],        wc1  = Wc[(ctb + 1) * 16 + l15];

    // hoist We2 b-frags: lane holds B[k = kk*32 + qd*8 + 0..7][c]
    short8 bf00, bf01, bf02, bf03, bf10, bf11, bf12, bf13;
    {
        const short* base0 = &we2t[(ctb * 16 + l15) * MP_ + qd * 8];
        const short* base1 = &we2t[((ctb + 1) * 16 + l15) * MP_ + qd * 8];
        bf00 = *(const short8*)(base0 + 0);
        bf01 = *(const short8*)(base0 + 32);
        bf02 = *(const short8*)(base0 + 64);
        bf03 = *(const short8*)(base0 + 96);
        bf10 = *(const short8*)(base1 + 0);
        bf11 = *(const short8*)(base1 + 32);
        bf12 = *(const short8*)(base1 + 64);
        bf13 = *(const short8*)(base1 + 96);
    }

    float aggP0 = 0, aggP1 = 0;
    float SP00 = 0, SP01 = 0, SP02 = 0, SP10 = 0, SP11 = 0, SP12 = 0;

    for (int jt = 0; jt < 10; jt++) {
        short* mb = mbuf[jt & 1];
        // ---- compute m-tile [16][128] -> silu -> bf16 into LDS ----
#pragma unroll
        for (int t = 0; t < 4; t++) {
            int jl = w * 4 + t;
            int j = jt * 16 + jl;
            float m0 = 0.0f, m1v = 0.0f;
            if (j < N_) {
                const float* bp = &Bfeat[(bs * N_ + j) * H_ + c0];
                float bv0 = bp[0], bv1 = bp[1];
                float ds = distL[j], bo = bondL[j];
                m0  = silu_f(af0 + bv0 + ds * w80a + bo * w81a);
                m1v = silu_f(af1 + bv1 + ds * w80b + bo * w81b);
            }
            unsigned pk = (unsigned)f2bf(m0) | ((unsigned)f2bf(m1v) << 16);
            *(unsigned*)&mb[jl * MP_ + c0] = pk;
        }
        __syncthreads();

        // ---- MFMA: [16j x 128k] @ [128k x 32c(wave)] ----
        float4v acc0 = {0, 0, 0, 0}, acc1 = {0, 0, 0, 0};
        const short* arow = &mb[l15 * MP_ + qd * 8];
        short8 a0 = *(const short8*)(arow + 0);
        short8 a1 = *(const short8*)(arow + 32);
        short8 a2 = *(const short8*)(arow + 64);
        short8 a3 = *(const short8*)(arow + 96);
        acc0 = __builtin_amdgcn_mfma_f32_16x16x32_bf16(a0, bf00, acc0, 0, 0, 0);
        acc1 = __builtin_amdgcn_mfma_f32_16x16x32_bf16(a0, bf10, acc1, 0, 0, 0);
        acc0 = __builtin_amdgcn_mfma_f32_16x16x32_bf16(a1, bf01, acc0, 0, 0, 0);
        acc1 = __builtin_amdgcn_mfma_f32_16x16x32_bf16(a1, bf11, acc1, 0, 0, 0);
        acc0 = __builtin_amdgcn_mfma_f32_16x16x32_bf16(a2, bf02, acc0, 0, 0, 0);
        acc1 = __builtin_amdgcn_mfma_f32_16x16x32_bf16(a2, bf12, acc1, 0, 0, 0);
        acc0 = __builtin_amdgcn_mfma_f32_16x16x32_bf16(a3, bf03, acc0, 0, 0, 0);
        acc1 = __builtin_amdgcn_mfma_f32_16x16x32_bf16(a3, bf13, acc1, 0, 0, 0);

        // ---- epilogue: silu, mask, reduce over j ----
#pragma unroll
        for (int r = 0; r < 4; r++) {
            int j = jt * 16 + qd * 4 + r;
            float em = emL[j];
            float d0 = diffL[j * 3 + 0];
            float d1 = diffL[j * 3 + 1];
            float d2 = diffL[j * 3 + 2];
            float mv0 = silu_f(acc0[r] + b2r0) * em;
            float mv1 = silu_f(acc1[r] + b2r1) * em;
            aggP0 += mv0; aggP1 += mv1;
            SP00 += d0 * mv0; SP01 += d1 * mv0; SP02 += d2 * mv0;
            SP10 += d0 * mv1; SP11 += d1 * mv1; SP12 += d2 * mv1;
        }
    }

    // ---- cross-quad reduction (rows j live in quads) ----
#define QR_(v) { v += __shfl_xor(v, 16, 64); v += __shfl_xor(v, 32, 64); }
    QR_(aggP0) QR_(aggP1)
    QR_(SP00) QR_(SP01) QR_(SP02)
    QR_(SP10) QR_(SP11) QR_(SP12)
#undef QR_

    if (qd == 0) {
        agg_out[node * H_ + ctb * 16 + l15]       = aggP0;
        agg_out[node * H_ + (ctb + 1) * 16 + l15] = aggP1;
    }

    // deferred cw: x_d = sum_c Wc[c]*S[d][c] + bc*Dsum[d]
    float p0 = wc0 * SP00 + wc1 * SP10;
    float p1 = wc0 * SP01 + wc1 * SP11;
    float p2 = wc0 * SP02 + wc1 * SP12;
    for (int s = 1; s < 16; s <<= 1) {
        p0 += __shfl_xor(p0, s, 64);
        p1 += __shfl_xor(p1, s, 64);
        p2 += __shfl_xor(p2, s, 64);
    }
    if (lane == 0) { wpart[w][0] = p0; wpart[w][1] = p1; wpart[w][2] = p2; }
    __syncthreads();
    if (tid < 3) {
        float tot = wpart[0][tid] + wpart[1][tid] + wpart[2][tid] + wpart[3][tid]
                  + bcp[0] * DsumL[tid];
        x_out[node * 3 + tid] = x_in[node * 3 + tid] + tot * (1.0f / (float)(N_ - 1));
    }
}

// ---------------- h update: h_out = silu([h, agg] @ Wh + bh) ----------------
__global__ void hupd_kernel(const float* __restrict__ h_in,
                            const float* __restrict__ agg,
                            const float* __restrict__ Wh,   // [F+H, F]
                            const float* __restrict__ bh,   // [F]
                            float* __restrict__ h_out) {
    int nb = blockIdx.x;      // bs*N + i
    int tid = threadIdx.x;    // 64
    __shared__ float cat[F_ + H_];
    if (tid < F_) cat[tid] = h_in[nb * F_ + tid];
    cat[F_ + tid]      = agg[nb * H_ + tid];
    cat[F_ + 64 + tid] = agg[nb * H_ + 64 + tid];
    __syncthreads();
    if (tid < F_) {
        float acc = bh[tid];
#pragma unroll 8
        for (int k = 0; k < F_ + H_; k++) acc += cat[k] * Wh[k * F_ + tid];
        h_out[nb * F_ + tid] = silu_f(acc);
    }
}

// ---------------- output: (x - x0) * atom_mask ----------------
__global__ void final_kernel(const float* __restrict__ xc,
                             const float* __restrict__ x0,
                             const float* __restrict__ amask,
                             float* __restrict__ out) {
    int idx = blockIdx.x * blockDim.x + threadIdx.x;
    if (idx >= B_ * S_ * N_ * 3) return;
    int i = (idx / 3) % N_;
    int b = idx / (3 * N_ * S_);
    out[idx] = (xc[idx] - x0[idx]) * amask[b * N_ + i];
}

extern "C" void kernel_launch(void* const* d_in, const int* in_sizes, int n_in,
                              void* d_out, int out_size, void* d_ws, size_t ws_size,
                              hipStream_t stream) {
    const float* t     = (const float*)d_in[0];
    const float* x     = (const float*)d_in[1];
    const int*   pep   = (const int*)d_in[2];
    const int*   labels= (const int*)d_in[3];
    const int*   aapos = (const int*)d_in[4];
    const float* bond  = (const float*)d_in[5];
    const float* em    = (const float*)d_in[6];
    const float* amask = (const float*)d_in[7];
    const float* R     = (const float*)d_in[8];
    const float* W_e1  = (const float*)d_in[9];
    const float* b_e1  = (const float*)d_in[10];
    const float* W_e2  = (const float*)d_in[11];
    const float* b_e2  = (const float*)d_in[12];
    const float* W_c   = (const float*)d_in[13];
    const float* b_c   = (const float*)d_in[14];
    const float* W_h   = (const float*)d_in[15];
    const float* b_h   = (const float*)d_in[16];
    const float* w_t   = (const float*)d_in[17];
    const float* w_b_t = (const float*)d_in[18];
    const float* tW_e1 = (const float*)d_in[19];
    const float* tb_e1 = (const float*)d_in[20];
    const float* tW_e2 = (const float*)d_in[21];
    const float* tb_e2 = (const float*)d_in[22];
    const float* tW_c  = (const float*)d_in[23];
    const float* tb_c  = (const float*)d_in[24];
    float* out = (float*)d_out;

    float* ws  = (float*)d_ws;
    float* x0  = ws;                 // 7200
    float* xA  = x0 + 7200;          // 7200
    float* xB  = xA + 7200;          // 7200
    float* hA  = xB + 7200;          // 96000
    float* hB  = hA + 96000;         // 96000
    float* agg = hB + 96000;         // 307200
    float* Af  = agg + 307200;       // 307200
    float* Bf  = Af + 307200;        // 307200  (total ~4.6 MB)

    const int XE = B_ * S_ * N_ * 3;   // 7200
    const int NB = B_ * S_ * N_;       // 2400

    init_h_kernel<<<(B_ * N_ * F_ + 255) / 256, 256, 0, stream>>>(pep, labels, aapos, hA);
    restore_x_kernel<<<(XE + 255) / 256, 256, 0, stream>>>(x, R, xA, x0);

    // ---- layer 0 ----
    ab_kernel<<<NB, H_, 0, stream>>>(hA, W_e1, b_e1, t, w_t, w_b_t, 1, Af, Bf);
    edge_kernel<<<NB, 256, 0, stream>>>(xA, Af, Bf, W_e1, W_e2, b_e2, W_c, b_c,
                                        bond, em, xB, agg);
    hupd_kernel<<<NB, 64, 0, stream>>>(hA, agg, W_h, b_h, hB);

    // ---- layer 1 ----
    ab_kernel<<<NB, H_, 0, stream>>>(hB, W_e1 + EF_ * H_, b_e1 + H_, t,
                                     w_t + H_, w_b_t + H_, 1, Af, Bf);
    edge_kernel<<<NB, 256, 0, stream>>>(xB, Af, Bf, W_e1 + EF_ * H_, W_e2 + H_ * H_,
                                        b_e2 + H_, W_c + H_, b_c + 1, bond, em, xA, agg);
    hupd_kernel<<<NB, 64, 0, stream>>>(hB, agg, W_h + (F_ + H_) * F_, b_h + F_, hA);

    // ---- t layer (no temb; final h unused) ----
    ab_kernel<<<NB, H_, 0, stream>>>(hA, tW_e1, tb_e1, nullptr, nullptr, nullptr, 0, Af, Bf);
    edge_kernel<<<NB, 256, 0, stream>>>(xA, Af, Bf, tW_e1, tW_e2, tb_e2, tW_c, tb_c,
                                        bond, em, xB, agg);

    final_kernel<<<(XE + 255) / 256, 256, 0, stream>>>(xB, x0, amask, out);
}

// Round 3
// 276.999 us; speedup vs baseline: 6.0780x; 1.4285x over previous
//
#include <hip/hip_runtime.h>
#include <math.h>

#define B_ 2
#define S_ 8
#define N_ 150
#define H_ 128
#define F_ 40
#define EF_ 82
#define NP_ 160            // N padded to 10 j-tiles of 16
#define MPQ 136            // mbuf row pitch in bf16 elems (128 + 8 pad)

typedef __attribute__((ext_vector_type(8))) short short8;
typedef __attribute__((ext_vector_type(4))) float float4v;

__device__ __forceinline__ float silu_f(float v) {
    return v * __builtin_amdgcn_rcpf(1.0f + __expf(-v));
}

// fp32 -> bf16 bits, round-to-nearest-even (must stay identical across rounds)
__device__ __forceinline__ unsigned short f2bf(float f) {
    unsigned u = __builtin_bit_cast(unsigned, f);
    return (unsigned short)((u + 0x7fffu + ((u >> 16) & 1u)) >> 16);
}

// ---------------- one-time: pack all 3 layers' We2 -> bf16 transposed [c][k] ----
__global__ void pack_we2_kernel(const float* __restrict__ w0,
                                const float* __restrict__ w1,
                                const float* __restrict__ w2,
                                unsigned short* __restrict__ outp) {
    int e = blockIdx.x * blockDim.x + threadIdx.x;   // 3*16384
    int l = e >> 14, idx = e & 16383;
    int k = idx >> 7, c = idx & 127;
    const float* src = (l == 0) ? w0 : (l == 1) ? w1 : w2;
    outp[l * 16384 + c * H_ + k] = f2bf(src[idx]);
}

// ---------------- restore absolute coords ----------------
__global__ void restore_x_kernel(const float* __restrict__ x,
                                 const float* __restrict__ R,
                                 float* __restrict__ xa,
                                 float* __restrict__ x0) {
    int idx = blockIdx.x * blockDim.x + threadIdx.x;
    if (idx >= B_ * S_ * N_ * 3) return;
    int d = idx % 3;
    int i = (idx / 3) % N_;
    int bs = idx / (3 * N_);
    int b = bs / S_;
    const float* xrow = x + bs * N_ * 3 + d;
    const float* Rrow = R + (b * N_ + i) * N_;
    float acc = 0.0f;
    for (int j = 0; j < N_; j++) acc += xrow[j * 3] * Rrow[j];
    xa[idx] = acc;
    x0[idx] = acc;
}

// ---------------- layer-0 node: one-hot h0 + Af/Bf via 3-row gather ----------------
// h0 is one-hot concat -> h0 @ We1[0:40] = We1[al] + We1[5+aa] + We1[25+ap-1]
__global__ void node0_kernel(const int* __restrict__ pep,
                             const int* __restrict__ labels,
                             const int* __restrict__ aapos,
                             const float* __restrict__ We1,
                             const float* __restrict__ be1,
                             const float* __restrict__ tp,
                             const float* __restrict__ wt,
                             const float* __restrict__ wbt,
                             float* __restrict__ h0,
                             float* __restrict__ Af,
                             float* __restrict__ Bf) {
    int bi = blockIdx.x;              // b*N + i
    int b = bi / N_, i = bi % N_;
    int c = threadIdx.x;              // 128
    int al = labels[bi];
    int ap = aapos[bi];               // 1..15
    int aa = pep[b * 15 + ap - 1];
    int r0 = al, r1 = 5 + aa, r2 = 25 + ap - 1;
    float fa = We1[r0 * H_ + c] + We1[r1 * H_ + c] + We1[r2 * H_ + c]
             + be1[c] + tp[b] * wt[c] + wbt[c];
    float fb = We1[(F_ + r0) * H_ + c] + We1[(F_ + r1) * H_ + c] + We1[(F_ + r2) * H_ + c];
    float hv = 0.0f;
    if (c < F_) hv = (c == r0 || c == r1 || c == r2) ? 1.0f : 0.0f;
    for (int s = 0; s < S_; s++) {
        int n = (b * S_ + s) * N_ + i;
        Af[n * H_ + c] = fa;
        Bf[n * H_ + c] = fb;
        if (c < F_) h0[n * F_ + c] = hv;
    }
}

// ---------------- fused node: h_out = silu([h,agg]@Wh+bh); Af/Bf for next layer ----
__global__ void node_kernel(const float* __restrict__ h_in,
                            const float* __restrict__ agg,
                            const float* __restrict__ Wh,    // [168,40]
                            const float* __restrict__ bh,    // [40]
                            const float* __restrict__ We1n,  // next layer [82,128]
                            const float* __restrict__ be1n,
                            const float* __restrict__ tp,
                            const float* __restrict__ wtn,
                            const float* __restrict__ wbtn,
                            int has_t,
                            float* __restrict__ h_out,
                            float* __restrict__ Af,
                            float* __restrict__ Bf) {
    int n = blockIdx.x;               // bs*N + node
    int b = n / (S_ * N_);
    int tid = threadIdx.x;            // 128
    __shared__ float cat[F_ + H_];    // 168
    __shared__ float part[120];
    __shared__ float hnew[F_];
    if (tid < F_) cat[tid] = h_in[n * F_ + tid];
    cat[F_ + tid] = agg[n * H_ + tid];
    __syncthreads();
    if (tid < 120) {
        int f = tid % 40, ks = tid / 40;   // 3-way k-split of 168 = 3*56
        float p = 0.0f;
        int k0 = ks * 56;
#pragma unroll 8
        for (int k = k0; k < k0 + 56; k++) p += cat[k] * Wh[k * F_ + f];
        part[tid] = p;
    }
    __syncthreads();
    if (tid < F_) {
        float hv = silu_f(part[tid] + part[40 + tid] + part[80 + tid] + bh[tid]);
        hnew[tid] = hv;
        h_out[n * F_ + tid] = hv;
    }
    __syncthreads();
    float fa = be1n[tid] + (has_t ? tp[b] * wtn[tid] + wbtn[tid] : 0.0f);
    float fb = 0.0f;
#pragma unroll 8
    for (int k = 0; k < F_; k++) {
        float hv = hnew[k];
        fa += hv * We1n[k * H_ + tid];
        fb += hv * We1n[(F_ + k) * H_ + tid];
    }
    Af[n * H_ + tid] = fa;
    Bf[n * H_ + tid] = fb;
}

// ---------------- edge kernel: block per (bs,i) ----------------
__global__ __launch_bounds__(256, 4) void edge_kernel(
    const float* __restrict__ x_in,    // [BS*N,3]
    const float* __restrict__ Afeat,   // [BS*N,128]
    const float* __restrict__ Bfeat,   // [BS*N,128]
    const float* __restrict__ We1,     // [82,128] rows 80/81 (dist,bond cols)
    const unsigned short* __restrict__ we2t,  // [128c][128k] bf16
    const float* __restrict__ be2,
    const float* __restrict__ Wc,
    const float* __restrict__ bcp,
    const float* __restrict__ bond,
    const float* __restrict__ emask,
    const float* __restrict__ x0v,     // final mode only
    const float* __restrict__ amask,   // final mode only
    int final_mode,
    float* __restrict__ x_out,         // xnew, or final output
    float* __restrict__ agg_out)
{
    __shared__ __align__(16) short mbuf[2][16 * MPQ];   // 8.7 KB
    __shared__ float4 diffE[NP_];                       // d0,d1,d2,em
    __shared__ float2 dbL[NP_];                         // dist, bond
    __shared__ float DsumL[3];
    __shared__ float wpart[4][3];

    int blk = blockIdx.x;
    int i = blk % N_, bs = blk / N_, b = bs / S_;
    int tid = threadIdx.x;
    int node = bs * N_ + i;
    int lane = tid & 63, w = tid >> 6;
    int qd = lane >> 4, l15 = lane & 15;
    int rowLoc = tid >> 4, c0 = (tid & 15) * 8;

    float xi0 = x_in[node * 3 + 0];
    float xi1 = x_in[node * 3 + 1];
    float xi2 = x_in[node * 3 + 2];

    // ---- stage per-j scalars ----
    if (tid < NP_) {
        int j = tid;
        float xj0 = xi0, xj1 = xi1, xj2 = xi2, bnd = 0.0f, emv = 0.0f;
        if (j < N_) {
            int nj = bs * N_ + j;
            xj0 = x_in[nj * 3 + 0];
            xj1 = x_in[nj * 3 + 1];
            xj2 = x_in[nj * 3 + 2];
            int eij = (b * N_ + i) * N_ + j;
            bnd = bond[eij];
            emv = (j == i) ? 0.0f : emask[eij];
        }
        float d0 = xi0 - xj0, d1 = xi1 - xj1, d2 = xi2 - xj2;
        diffE[j] = make_float4(d0, d1, d2, emv);
        dbL[j] = make_float2(sqrtf(d0 * d0 + d1 * d1 + d2 * d2 + 1e-12f), bnd);
    }

    // ---- hoisted m-compute constants: this thread's 8 channels ----
    float afr[8], w80r[8], w81r[8];
    {
        float4 t0 = *(const float4*)&Afeat[node * H_ + c0];
        float4 t1 = *(const float4*)&Afeat[node * H_ + c0 + 4];
        afr[0]=t0.x; afr[1]=t0.y; afr[2]=t0.z; afr[3]=t0.w;
        afr[4]=t1.x; afr[5]=t1.y; afr[6]=t1.z; afr[7]=t1.w;
        t0 = *(const float4*)&We1[80 * H_ + c0];
        t1 = *(const float4*)&We1[80 * H_ + c0 + 4];
        w80r[0]=t0.x; w80r[1]=t0.y; w80r[2]=t0.z; w80r[3]=t0.w;
        w80r[4]=t1.x; w80r[5]=t1.y; w80r[6]=t1.z; w80r[7]=t1.w;
        t0 = *(const float4*)&We1[81 * H_ + c0];
        t1 = *(const float4*)&We1[81 * H_ + c0 + 4];
        w81r[0]=t0.x; w81r[1]=t0.y; w81r[2]=t0.z; w81r[3]=t0.w;
        w81r[4]=t1.x; w81r[5]=t1.y; w81r[6]=t1.z; w81r[7]=t1.w;
    }

    // ---- epilogue constants + hoisted We2 b-frags (L1-cached global) ----
    int ctb = w * 2;
    float b2r0 = be2[ctb * 16 + l15],  b2r1 = be2[ctb * 16 + 16 + l15];
    float wc0  = Wc[ctb * 16 + l15],   wc1  = Wc[ctb * 16 + 16 + l15];
    const unsigned short* bb0 = we2t + (ctb * 16 + l15) * H_ + qd * 8;
    const unsigned short* bb1 = bb0 + 16 * H_;
    short8 bf00 = *(const short8*)(bb0 +  0);
    short8 bf01 = *(const short8*)(bb0 + 32);
    short8 bf02 = *(const short8*)(bb0 + 64);
    short8 bf03 = *(const short8*)(bb0 + 96);
    short8 bf10 = *(const short8*)(bb1 +  0);
    short8 bf11 = *(const short8*)(bb1 + 32);
    short8 bf12 = *(const short8*)(bb1 + 64);
    short8 bf13 = *(const short8*)(bb1 + 96);

    __syncthreads();

    // ---- Dsum[d] = sum_j diff (wave 0) ----
    if (w == 0) {
        float p0 = 0, p1 = 0, p2 = 0;
        for (int j = lane; j < NP_; j += 64) {
            float4 d = diffE[j];
            p0 += d.x; p1 += d.y; p2 += d.z;
        }
        for (int s = 1; s < 64; s <<= 1) {
            p0 += __shfl_xor(p0, s, 64);
            p1 += __shfl_xor(p1, s, 64);
            p2 += __shfl_xor(p2, s, 64);
        }
        if (lane == 0) { DsumL[0] = p0; DsumL[1] = p1; DsumL[2] = p2; }
    }

    float aggP0 = 0, aggP1 = 0;
    float SP00 = 0, SP01 = 0, SP02 = 0, SP10 = 0, SP11 = 0, SP12 = 0;

    for (int jt = 0; jt < 10; jt++) {
        short* mb = mbuf[jt & 1];
        // ---- m-compute: this thread's row (rowLoc), 8 channels ----
        int jrow = jt * 16 + rowLoc;
        float mv[8];
        if (jrow < N_) {
            const float* bp = &Bfeat[(bs * N_ + jrow) * H_ + c0];
            float4 b0 = *(const float4*)bp;
            float4 b1 = *(const float4*)(bp + 4);
            float br[8] = {b0.x, b0.y, b0.z, b0.w, b1.x, b1.y, b1.z, b1.w};
            float2 db = dbL[jrow];
#pragma unroll
            for (int u = 0; u < 8; u++)
                mv[u] = silu_f(afr[u] + br[u] + db.x * w80r[u] + db.y * w81r[u]);
        } else {
#pragma unroll
            for (int u = 0; u < 8; u++) mv[u] = 0.0f;
        }
        short8 pkv;
#pragma unroll
        for (int u = 0; u < 8; u++) pkv[u] = (short)f2bf(mv[u]);
        *(short8*)&mb[rowLoc * MPQ + c0] = pkv;
        __syncthreads();

        // ---- MFMA [16j x 128k] @ [128k x 32c per wave] ----
        const short* arow = &mb[l15 * MPQ + qd * 8];
        short8 a0 = *(const short8*)(arow +  0);
        short8 a1 = *(const short8*)(arow + 32);
        short8 a2 = *(const short8*)(arow + 64);
        short8 a3 = *(const short8*)(arow + 96);
        float4v acc0 = {0, 0, 0, 0}, acc1 = {0, 0, 0, 0};
        acc0 = __builtin_amdgcn_mfma_f32_16x16x32_bf16(a0, bf00, acc0, 0, 0, 0);
        acc1 = __builtin_amdgcn_mfma_f32_16x16x32_bf16(a0, bf10, acc1, 0, 0, 0);
        acc0 = __builtin_amdgcn_mfma_f32_16x16x32_bf16(a1, bf01, acc0, 0, 0, 0);
        acc1 = __builtin_amdgcn_mfma_f32_16x16x32_bf16(a1, bf11, acc1, 0, 0, 0);
        acc0 = __builtin_amdgcn_mfma_f32_16x16x32_bf16(a2, bf02, acc0, 0, 0, 0);
        acc1 = __builtin_amdgcn_mfma_f32_16x16x32_bf16(a2, bf12, acc1, 0, 0, 0);
        acc0 = __builtin_amdgcn_mfma_f32_16x16x32_bf16(a3, bf03, acc0, 0, 0, 0);
        acc1 = __builtin_amdgcn_mfma_f32_16x16x32_bf16(a3, bf13, acc1, 0, 0, 0);

        // ---- epilogue: silu, mask, reduce over rows ----
#pragma unroll
        for (int r = 0; r < 4; r++) {
            int j = jt * 16 + qd * 4 + r;
            float4 de = diffE[j];
            float mv0 = silu_f(acc0[r] + b2r0) * de.w;
            float mv1 = silu_f(acc1[r] + b2r1) * de.w;
            aggP0 += mv0; aggP1 += mv1;
            SP00 += de.x * mv0; SP01 += de.y * mv0; SP02 += de.z * mv0;
            SP10 += de.x * mv1; SP11 += de.y * mv1; SP12 += de.z * mv1;
        }
    }

    // ---- cross-quad reduction (rows live in quads) ----
#define QR_(v) { v += __shfl_xor(v, 16, 64); v += __shfl_xor(v, 32, 64); }
    QR_(aggP0) QR_(aggP1)
    QR_(SP00) QR_(SP01) QR_(SP02)
    QR_(SP10) QR_(SP11) QR_(SP12)
#undef QR_

    if (!final_mode && qd == 0) {
        agg_out[node * H_ + ctb * 16 + l15]      = aggP0;
        agg_out[node * H_ + ctb * 16 + 16 + l15] = aggP1;
    }

    // deferred cw: x_d += (sum_c Wc[c]*S[d][c] + bc*Dsum[d]) / (N-1)
    float p0 = wc0 * SP00 + wc1 * SP10;
    float p1 = wc0 * SP01 + wc1 * SP11;
    float p2 = wc0 * SP02 + wc1 * SP12;
    for (int s = 1; s < 16; s <<= 1) {
        p0 += __shfl_xor(p0, s, 64);
        p1 += __shfl_xor(p1, s, 64);
        p2 += __shfl_xor(p2, s, 64);
    }
    if (lane == 0) { wpart[w][0] = p0; wpart[w][1] = p1; wpart[w][2] = p2; }
    __syncthreads();
    if (tid < 3) {
        float tot = wpart[0][tid] + wpart[1][tid] + wpart[2][tid] + wpart[3][tid]
                  + bcp[0] * DsumL[tid];
        float xn = x_in[node * 3 + tid] + tot * (1.0f / (float)(N_ - 1));
        if (final_mode)
            x_out[node * 3 + tid] = (xn - x0v[node * 3 + tid]) * amask[b * N_ + i];
        else
            x_out[node * 3 + tid] = xn;
    }
}

extern "C" void kernel_launch(void* const* d_in, const int* in_sizes, int n_in,
                              void* d_out, int out_size, void* d_ws, size_t ws_size,
                              hipStream_t stream) {
    const float* t     = (const float*)d_in[0];
    const float* x     = (const float*)d_in[1];
    const int*   pep   = (const int*)d_in[2];
    const int*   labels= (const int*)d_in[3];
    const int*   aapos = (const int*)d_in[4];
    const float* bond  = (const float*)d_in[5];
    const float* em    = (const float*)d_in[6];
    const float* amask = (const float*)d_in[7];
    const float* R     = (const float*)d_in[8];
    const float* W_e1  = (const float*)d_in[9];
    const float* b_e1  = (const float*)d_in[10];
    const float* W_e2  = (const float*)d_in[11];
    const float* b_e2  = (const float*)d_in[12];
    const float* W_c   = (const float*)d_in[13];
    const float* b_c   = (const float*)d_in[14];
    const float* W_h   = (const float*)d_in[15];
    const float* b_h   = (const float*)d_in[16];
    const float* w_t   = (const float*)d_in[17];
    const float* w_b_t = (const float*)d_in[18];
    const float* tW_e1 = (const float*)d_in[19];
    const float* tb_e1 = (const float*)d_in[20];
    const float* tW_e2 = (const float*)d_in[21];
    const float* tb_e2 = (const float*)d_in[22];
    const float* tW_c  = (const float*)d_in[23];
    const float* tb_c  = (const float*)d_in[24];
    float* out = (float*)d_out;

    float* ws = (float*)d_ws;
    unsigned short* we2t = (unsigned short*)ws;   // 49152 shorts = 24576 floats
    float* x0  = ws + 24576;         // 7200
    float* xA  = x0 + 7200;          // 7200
    float* xB  = xA + 7200;          // 7200
    float* hA  = xB + 7200;          // 96000
    float* hB  = hA + 96000;         // 96000
    float* agg = hB + 96000;         // 307200
    float* Af  = agg + 307200;       // 307200
    float* Bf  = Af + 307200;        // 307200  (~4.65 MB total)

    const int XE = B_ * S_ * N_ * 3;   // 7200
    const int NB = B_ * S_ * N_;       // 2400

    pack_we2_kernel<<<48, 1024, 0, stream>>>(W_e2, W_e2 + H_ * H_, tW_e2, we2t);
    restore_x_kernel<<<(XE + 255) / 256, 256, 0, stream>>>(x, R, xA, x0);
    node0_kernel<<<B_ * N_, H_, 0, stream>>>(pep, labels, aapos, W_e1, b_e1,
                                             t, w_t, w_b_t, hA, Af, Bf);

    // ---- layer 0 ----
    edge_kernel<<<NB, 256, 0, stream>>>(xA, Af, Bf, W_e1, we2t, b_e2, W_c, b_c,
                                        bond, em, nullptr, nullptr, 0, xB, agg);
    node_kernel<<<NB, H_, 0, stream>>>(hA, agg, W_h, b_h,
                                       W_e1 + EF_ * H_, b_e1 + H_,
                                       t, w_t + H_, w_b_t + H_, 1, hB, Af, Bf);

    // ---- layer 1 ----
    edge_kernel<<<NB, 256, 0, stream>>>(xB, Af, Bf, W_e1 + EF_ * H_, we2t + 16384,
                                        b_e2 + H_, W_c + H_, b_c + 1,
                                        bond, em, nullptr, nullptr, 0, xA, agg);
    node_kernel<<<NB, H_, 0, stream>>>(hB, agg, W_h + (F_ + H_) * F_, b_h + F_,
                                       tW_e1, tb_e1,
                                       nullptr, nullptr, nullptr, 0, hA, Af, Bf);

    // ---- t layer: fused final output ----
    edge_kernel<<<NB, 256, 0, stream>>>(xA, Af, Bf, tW_e1, we2t + 32768,
                                        tb_e2, tW_c, tb_c,
                                        bond, em, x0, amask, 1, out, agg);
}